// Round 14
// baseline (6354.187 us; speedup 1.0000x reference)
//
#include <hip/hip_runtime.h>
#include <stdint.h>

#define B_  256
#define T_  512
#define IN_ 64
#define H_  512
#define G4_ 2048
#define NC_ 64
#define H2_ 256

typedef _Float16 f16;
typedef __attribute__((ext_vector_type(4))) _Float16 f16x4;
typedef __attribute__((ext_vector_type(4))) float    f32x4;
typedef __attribute__((ext_vector_type(4))) unsigned int u32x4;

__device__ __forceinline__ float sigf(float x) {
  return __builtin_amdgcn_rcpf(1.0f + __expf(-x));
}
__device__ __forceinline__ float tanh_fast(float x) {
  x = fminf(fmaxf(x, -15.f), 15.f);
  const float e = __expf(2.f * x);
  return (e - 1.f) * __builtin_amdgcn_rcpf(e + 1.f);
}
// AGPR pin (round-13 mechanism, now on a 64-reg footprint that can fit)
__device__ __forceinline__ void pinA(f16x4& v) {
  asm volatile("" : "+a"(v));
}

// L3-coherent (cache-bypassing) helpers; wait_vm0 before consuming results.
__device__ __forceinline__ void store_u32_l3(void* p, unsigned v) {
  asm volatile("global_store_dword %0, %1, off sc0 sc1" :: "v"(p), "v"(v) : "memory");
}
__device__ __forceinline__ unsigned load_u32_l3(const void* p) {
  unsigned r;
  asm volatile("global_load_dword %0, %1, off sc0 sc1" : "=v"(r) : "v"(p) : "memory");
  return r;
}
__device__ __forceinline__ u32x4 load_u32x4_l3(const void* p) {
  u32x4 r;
  asm volatile("global_load_dwordx4 %0, %1, off sc0 sc1" : "=v"(r) : "v"(p) : "memory");
  return r;
}
__device__ __forceinline__ void wait_vm0() {
  asm volatile("s_waitcnt vmcnt(0)" ::: "memory");
}
// flag poll with monotonic cache: skips the L3 RT when already satisfied
__device__ __forceinline__ void poll_ge(const unsigned* p, unsigned want, unsigned& seen) {
  if (__all((int)(seen >= want))) return;
  for (;;) {
    unsigned v = load_u32_l3(p);
    wait_vm0();
    seen = v;
    if (__all((int)(v >= want))) return;
    __builtin_amdgcn_s_sleep(1);
  }
}

// ---------------- prep kernels ----------------
__global__ void cvt_f32_f16(const float* __restrict__ s, f16* __restrict__ d, int n) {
  int i = blockIdx.x * blockDim.x + threadIdx.x;
  int st = gridDim.x * blockDim.x;
  for (; i < n; i += st) d[i] = (f16)s[i];
}

__global__ void bias_comb(const float* __restrict__ a, const float* __restrict__ b,
                          float* __restrict__ d, int n) {
  int i = blockIdx.x * blockDim.x + threadIdx.x;
  if (i < n) d[i] = a[i] + b[i];
}

// ---------------- fused pipelined 2-layer LSTM, 2 roles ----------------
// 256 WGs x 512 threads, 1 WG/CU. Per-WG tile: M=32 batch rows, N=128 gate
// rows (32 h-cols) -> recurrence weights = 64 regs/thread (residency-viable).
// role A (bid 0..127):   layer-0 scan (grp=bid>>4 of 8, sl=bid&15 of 16);
//                        whh0 pinned resident, wih0 streamed (16 KB/step).
// role C (bid 128..255): layer-1 scan; phase 1: gx1 = bias1 + wih1 . h0(t)
//                        (wih1 streamed 128 KB/step; h0 ready early — A runs
//                        ahead); phase 2: + whh1 . h1(t-1), whh1 pinned.
// One 34 KB LDS buffer per WG serially reused: h0-tile -> h1-tile -> gl alias.
// flags: slot i at flags[i*16]; A: grp*16+sl, C: 128+grp*16+sl; value = steps done.
__global__ __launch_bounds__(512, 2) void fused_g(
    const f16* __restrict__ x16,     // [B][T][64]
    const f16* __restrict__ wih0,    // [2048][64]
    const f16* __restrict__ whh0,    // [2048][512]
    const f16* __restrict__ wih1,    // [2048][512]
    const f16* __restrict__ whh1,    // [2048][512]
    const float* __restrict__ bias0, // [2048]
    const float* __restrict__ bias1, // [2048]
    f16* __restrict__ h0seq,         // [T][B][512]
    f16* __restrict__ hbuf1,         // [2][B][512]
    unsigned* __restrict__ flags) {
  __shared__ __align__(16) unsigned char smem[38912];
  const int bid = blockIdx.x;
  const int tid = threadIdx.x;
  const int lane = tid & 63, wv = tid >> 6;        // 8 waves
  const int l15 = lane & 15, hi = lane >> 4;

  // common geometry
  const int lg = wv * 16 + l15;                    // local gate row 0..127 (1 N-tile/wave)
  const int row = tid >> 4;                        // owned batch row 0..31 (also staging row)
  const int j0 = (tid & 15) * 2;                   // owned h-col pair within 32
  const int hcol = (tid & 15) * 32;                // staging: 32 f16 = 64 B/thread

  if (bid < 128) {
    // ================= role A: layer-0 scan =================
    const int grp = bid >> 4, sl = bid & 15;
    f16 (*hb)[532]   = (f16(*)[532])smem;                    // 34048 B (h tile)
    float (*gl)[132] = (float(*)[132])smem;                  // alias of hb
    f16 (*xt)[72]    = (f16(*)[72])(smem + 34304);           // 4608 B

    const int grow = (lg >> 5) * H_ + sl * 32 + (lg & 31);
    const float bv = bias0[grow];
    const f16* wq = wih0 + (size_t)grow * IN_ + 4 * hi;      // streamed x-weights
    f16x4 bhh[32];
    {
      const f16* wp = whh0 + (size_t)grow * H_ + 4 * hi;
#pragma unroll
      for (int ks = 0; ks < 32; ++ks) { bhh[ks] = *(const f16x4*)(wp + ks * 16); pinA(bhh[ks]); }
    }

    float c0 = 0.f, c1 = 0.f;
    unsigned seen = 0;
    unsigned* myflag = flags + (size_t)(grp * 16 + sl) * 16;
    const unsigned* pollp = flags + (size_t)(grp * 16 + (lane & 15)) * 16;

    for (int t = 0; t < T_; ++t) {
#pragma unroll
      for (int ks = 0; ks < 32; ++ks) pinA(bhh[ks]);         // loop-carried residency

      uint4 xv = {};
      if (tid < 256)
        xv = *(const uint4*)(x16 + ((size_t)(grp * 32 + (tid >> 3)) * T_ + t) * IN_ + (tid & 7) * 8);
      if (t != 0) poll_ge(pollp, (unsigned)t, seen);
      if (tid < 256) *(uint4*)&xt[tid >> 3][(tid & 7) * 8] = xv;

      if (t != 0) {
        const f16* hs = h0seq + ((size_t)(t - 1) * B_ + grp * 32 + row) * H_ + hcol;
        u32x4 r0 = load_u32x4_l3(hs);
        u32x4 r1 = load_u32x4_l3(hs + 8);
        u32x4 r2 = load_u32x4_l3(hs + 16);
        u32x4 r3 = load_u32x4_l3(hs + 24);
        wait_vm0();
        __builtin_amdgcn_sched_barrier(0);
        *(u32x4*)&hb[row][hcol]      = r0;
        *(u32x4*)&hb[row][hcol + 8]  = r1;
        *(u32x4*)&hb[row][hcol + 16] = r2;
        *(u32x4*)&hb[row][hcol + 24] = r3;
      } else {
        u32x4 z = {0u, 0u, 0u, 0u};
        *(u32x4*)&hb[row][hcol]      = z;
        *(u32x4*)&hb[row][hcol + 8]  = z;
        *(u32x4*)&hb[row][hcol + 16] = z;
        *(u32x4*)&hb[row][hcol + 24] = z;
      }
      __syncthreads();

      f32x4 acc0, acc1;
      acc0[0] = bv; acc0[1] = bv; acc0[2] = bv; acc0[3] = bv;
      acc1 = acc0;
#pragma unroll
      for (int ks = 0; ks < 4; ++ks) {
        const f16x4 w  = *(const f16x4*)(wq + ks * 16);
        const f16x4 a0 = *(const f16x4*)&xt[l15][ks * 16 + 4 * hi];
        const f16x4 a1 = *(const f16x4*)&xt[16 + l15][ks * 16 + 4 * hi];
        acc0 = __builtin_amdgcn_mfma_f32_16x16x16f16(a0, w, acc0, 0, 0, 0);
        acc1 = __builtin_amdgcn_mfma_f32_16x16x16f16(a1, w, acc1, 0, 0, 0);
      }
#pragma unroll
      for (int ks = 0; ks < 32; ++ks) {
        const f16x4 a0 = *(const f16x4*)&hb[l15][ks * 16 + 4 * hi];
        const f16x4 a1 = *(const f16x4*)&hb[16 + l15][ks * 16 + 4 * hi];
        acc0 = __builtin_amdgcn_mfma_f32_16x16x16f16(a0, bhh[ks], acc0, 0, 0, 0);
        acc1 = __builtin_amdgcn_mfma_f32_16x16x16f16(a1, bhh[ks], acc1, 0, 0, 0);
      }
      __syncthreads();   // all hb reads done before gl alias write

      const int col = wv * 16 + l15;
#pragma unroll
      for (int r = 0; r < 4; ++r) gl[4 * hi + r][col] = acc0[r];
#pragma unroll
      for (int r = 0; r < 4; ++r) gl[16 + 4 * hi + r][col] = acc1[r];
      __syncthreads();

      const float gi = gl[row][j0],       gi1 = gl[row][j0 + 1];
      const float gf = gl[row][32 + j0],  gf1 = gl[row][32 + j0 + 1];
      const float gg = gl[row][64 + j0],  gg1 = gl[row][64 + j0 + 1];
      const float go = gl[row][96 + j0],  go1 = gl[row][96 + j0 + 1];
      c0 = sigf(gf) * c0 + sigf(gi) * tanh_fast(gg);
      c1 = sigf(gf1) * c1 + sigf(gi1) * tanh_fast(gg1);
      const f16 ha = (f16)(sigf(go) * tanh_fast(c0));
      const f16 hb2 = (f16)(sigf(go1) * tanh_fast(c1));
      unsigned hp = ((unsigned)__builtin_bit_cast(unsigned short, hb2) << 16)
                  |  (unsigned)__builtin_bit_cast(unsigned short, ha);
      store_u32_l3(h0seq + ((size_t)t * B_ + grp * 32 + row) * H_ + sl * 32 + j0, hp);
      wait_vm0();
      __syncthreads();
      if (tid == 0) store_u32_l3(myflag, (unsigned)(t + 1));
    }

  } else {
    // ================= role C: layer-1 scan, phase-split =================
    const int grp = (bid - 128) >> 4, sl = (bid - 128) & 15;
    f16 (*hb)[532]   = (f16(*)[532])smem;                    // h0 tile, then h1 tile
    float (*gl)[132] = (float(*)[132])smem;                  // alias of hb

    const int grow = (lg >> 5) * H_ + sl * 32 + (lg & 31);
    const float bv = bias1[grow];
    const f16* wq = wih1 + (size_t)grow * H_ + 4 * hi;       // streamed gx weights
    f16x4 bhh[32];
    {
      const f16* wp = whh1 + (size_t)grow * H_ + 4 * hi;
#pragma unroll
      for (int ks = 0; ks < 32; ++ks) { bhh[ks] = *(const f16x4*)(wp + ks * 16); pinA(bhh[ks]); }
    }

    float c0 = 0.f, c1 = 0.f;
    unsigned seenA = 0, seenC = 0;
    unsigned* myflag = flags + (size_t)(128 + grp * 16 + sl) * 16;
    const unsigned* pollA = flags + (size_t)(grp * 16 + (lane & 15)) * 16;
    const unsigned* pollC = flags + (size_t)(128 + grp * 16 + (lane & 15)) * 16;

    for (int t = 0; t < T_; ++t) {
#pragma unroll
      for (int ks = 0; ks < 32; ++ks) pinA(bhh[ks]);

      // ---- phase 1: stage h0(t), gx1 accumulate with streamed wih1 ----
      poll_ge(pollA, (unsigned)(t + 1), seenA);
      {
        const f16* hs = h0seq + ((size_t)t * B_ + grp * 32 + row) * H_ + hcol;
        u32x4 r0 = load_u32x4_l3(hs);
        u32x4 r1 = load_u32x4_l3(hs + 8);
        u32x4 r2 = load_u32x4_l3(hs + 16);
        u32x4 r3 = load_u32x4_l3(hs + 24);
        wait_vm0();
        __builtin_amdgcn_sched_barrier(0);
        *(u32x4*)&hb[row][hcol]      = r0;
        *(u32x4*)&hb[row][hcol + 8]  = r1;
        *(u32x4*)&hb[row][hcol + 16] = r2;
        *(u32x4*)&hb[row][hcol + 24] = r3;
      }
      __syncthreads();

      f32x4 acc0, acc1;
      acc0[0] = bv; acc0[1] = bv; acc0[2] = bv; acc0[3] = bv;
      acc1 = acc0;
#pragma unroll
      for (int ks = 0; ks < 32; ++ks) {
        const f16x4 w  = *(const f16x4*)(wq + ks * 16);      // L2-hot stream
        const f16x4 a0 = *(const f16x4*)&hb[l15][ks * 16 + 4 * hi];
        const f16x4 a1 = *(const f16x4*)&hb[16 + l15][ks * 16 + 4 * hi];
        acc0 = __builtin_amdgcn_mfma_f32_16x16x16f16(a0, w, acc0, 0, 0, 0);
        acc1 = __builtin_amdgcn_mfma_f32_16x16x16f16(a1, w, acc1, 0, 0, 0);
      }
      __syncthreads();   // phase-1 hb reads done

      // ---- phase 2: stage h1(t-1) into same buffer, resident whh1 ----
      if (t != 0) {
        poll_ge(pollC, (unsigned)t, seenC);
        const f16* hs = hbuf1 + ((size_t)((t - 1) & 1) * B_ + grp * 32 + row) * H_ + hcol;
        u32x4 r0 = load_u32x4_l3(hs);
        u32x4 r1 = load_u32x4_l3(hs + 8);
        u32x4 r2 = load_u32x4_l3(hs + 16);
        u32x4 r3 = load_u32x4_l3(hs + 24);
        wait_vm0();
        __builtin_amdgcn_sched_barrier(0);
        *(u32x4*)&hb[row][hcol]      = r0;
        *(u32x4*)&hb[row][hcol + 8]  = r1;
        *(u32x4*)&hb[row][hcol + 16] = r2;
        *(u32x4*)&hb[row][hcol + 24] = r3;
      } else {
        u32x4 z = {0u, 0u, 0u, 0u};
        *(u32x4*)&hb[row][hcol]      = z;
        *(u32x4*)&hb[row][hcol + 8]  = z;
        *(u32x4*)&hb[row][hcol + 16] = z;
        *(u32x4*)&hb[row][hcol + 24] = z;
      }
      __syncthreads();

#pragma unroll
      for (int ks = 0; ks < 32; ++ks) {
        const f16x4 a0 = *(const f16x4*)&hb[l15][ks * 16 + 4 * hi];
        const f16x4 a1 = *(const f16x4*)&hb[16 + l15][ks * 16 + 4 * hi];
        acc0 = __builtin_amdgcn_mfma_f32_16x16x16f16(a0, bhh[ks], acc0, 0, 0, 0);
        acc1 = __builtin_amdgcn_mfma_f32_16x16x16f16(a1, bhh[ks], acc1, 0, 0, 0);
      }
      __syncthreads();   // phase-2 hb reads done before gl alias write

      const int col = wv * 16 + l15;
#pragma unroll
      for (int r = 0; r < 4; ++r) gl[4 * hi + r][col] = acc0[r];
#pragma unroll
      for (int r = 0; r < 4; ++r) gl[16 + 4 * hi + r][col] = acc1[r];
      __syncthreads();

      const float gi = gl[row][j0],       gi1 = gl[row][j0 + 1];
      const float gf = gl[row][32 + j0],  gf1 = gl[row][32 + j0 + 1];
      const float gg = gl[row][64 + j0],  gg1 = gl[row][64 + j0 + 1];
      const float go = gl[row][96 + j0],  go1 = gl[row][96 + j0 + 1];
      c0 = sigf(gf) * c0 + sigf(gi) * tanh_fast(gg);
      c1 = sigf(gf1) * c1 + sigf(gi1) * tanh_fast(gg1);
      const f16 ha = (f16)(sigf(go) * tanh_fast(c0));
      const f16 hb2 = (f16)(sigf(go1) * tanh_fast(c1));
      unsigned hp = ((unsigned)__builtin_bit_cast(unsigned short, hb2) << 16)
                  |  (unsigned)__builtin_bit_cast(unsigned short, ha);
      store_u32_l3(hbuf1 + ((size_t)(t & 1) * B_ + grp * 32 + row) * H_ + sl * 32 + j0, hp);
      wait_vm0();
      __syncthreads();
      if (tid == 0) store_u32_l3(myflag, (unsigned)(t + 1));
    }
  }
}

// ---------------- MLP head ----------------
__global__ void head_g(const f16* __restrict__ h1, const float* __restrict__ w1,
                       const float* __restrict__ b1, const float* __restrict__ w2,
                       const float* __restrict__ b2, float* __restrict__ out) {
  __shared__ float ft[512];
  __shared__ float hm[256];
  const int b = blockIdx.x, tid = threadIdx.x;
  ft[tid * 2]     = (float)h1[(size_t)b * H_ + tid * 2];
  ft[tid * 2 + 1] = (float)h1[(size_t)b * H_ + tid * 2 + 1];
  __syncthreads();
  {
    float d = b1[tid];
    const float* wr = w1 + (size_t)tid * H_;
#pragma unroll 8
    for (int k = 0; k < H_; ++k) d += ft[k] * wr[k];
    hm[tid] = fmaxf(d, 0.f);
  }
  __syncthreads();
  if (tid < NC_) {
    float d = b2[tid];
    const float* wr = w2 + (size_t)tid * H2_;
#pragma unroll 8
    for (int k = 0; k < H2_; ++k) d += hm[k] * wr[k];
    out[(size_t)b * NC_ + tid] = d;
  }
}

// ---------------- launcher ----------------
extern "C" void kernel_launch(void* const* d_in, const int* in_sizes, int n_in,
                              void* d_out, int out_size, void* d_ws, size_t ws_size,
                              hipStream_t stream) {
  const float* x     = (const float*)d_in[0];
  const float* w_ih0 = (const float*)d_in[1];
  const float* w_hh0 = (const float*)d_in[2];
  const float* b_ih0 = (const float*)d_in[3];
  const float* b_hh0 = (const float*)d_in[4];
  const float* w_ih1 = (const float*)d_in[5];
  const float* w_hh1 = (const float*)d_in[6];
  const float* b_ih1 = (const float*)d_in[7];
  const float* b_hh1 = (const float*)d_in[8];
  const float* w1    = (const float*)d_in[9];
  const float* b1    = (const float*)d_in[10];
  const float* w2    = (const float*)d_in[11];
  const float* b2    = (const float*)d_in[12];
  float* out = (float*)d_out;

  char* p = (char*)d_ws;
  auto alloc = [&](size_t bytes) { char* r = p; p += (bytes + 255) & ~(size_t)255; return r; };
  f16*   h0seq  = (f16*)alloc((size_t)T_ * B_ * H_ * 2);        // 134 MB
  f16*   hbuf1  = (f16*)alloc((size_t)2 * B_ * H_ * 2);
  f16*   x16    = (f16*)alloc((size_t)B_ * T_ * IN_ * 2);
  f16*   wih0h  = (f16*)alloc((size_t)G4_ * IN_ * 2);
  f16*   whh0h  = (f16*)alloc((size_t)G4_ * H_ * 2);
  f16*   wih1h  = (f16*)alloc((size_t)G4_ * H_ * 2);
  f16*   whh1h  = (f16*)alloc((size_t)G4_ * H_ * 2);
  float* bias0c = (float*)alloc(G4_ * 4);
  float* bias1c = (float*)alloc(G4_ * 4);
  unsigned* flags = (unsigned*)alloc(256 * 64);

  hipMemsetAsync(flags, 0, 256 * 64, stream);
  cvt_f32_f16<<<2048, 256, 0, stream>>>(x, x16, B_ * T_ * IN_);
  cvt_f32_f16<<<512, 256, 0, stream>>>(w_ih0, wih0h, G4_ * IN_);
  cvt_f32_f16<<<2048, 256, 0, stream>>>(w_hh0, whh0h, G4_ * H_);
  cvt_f32_f16<<<2048, 256, 0, stream>>>(w_ih1, wih1h, G4_ * H_);
  cvt_f32_f16<<<2048, 256, 0, stream>>>(w_hh1, whh1h, G4_ * H_);
  bias_comb<<<8, 256, 0, stream>>>(b_ih0, b_hh0, bias0c, G4_);
  bias_comb<<<8, 256, 0, stream>>>(b_ih1, b_hh1, bias1c, G4_);

  fused_g<<<256, 512, 0, stream>>>(x16, wih0h, whh0h, wih1h, whh1h,
                                   bias0c, bias1c, h0seq, hbuf1, flags);
  head_g<<<B_, 256, 0, stream>>>(hbuf1 + (size_t)B_ * H_, w1, b1, w2, b2, out);
}